// Round 1
// baseline (27.376 us; speedup 1.0000x reference)
//
#include <hip/hip_runtime.h>
#include <math.h>

// PMSN Vandermonde kernel: out[h,l] = Re( sum_n C*B_bar * exp(dt*A)^l )
// H=2048, N=4, L=8192 -> 16.7M fp32 outputs (64 MiB, write-bound).
//
// Per (h,n) we precompute:
//   a2  = dt*A_real * log2(e)        (exp2 decay coefficient per step)
//   thr = dt*A_imag / (2*pi)         (revolutions per step)
//   R, phr: w = C*B_bar = R*e^{i*phi};  phr = phi/(2*pi)
// Then out[h,l] = sum_n R_n * exp2(a2_n*l) * cos(2*pi*fract(thr_n*l + phr_n))
// i.e. 2 transcendentals + 4 full-rate VALU per (element, n).

#define HH 2048
#define NN 4
#define LL 8192

__global__ __launch_bounds__(256) void pmsn_kernel(
    const float* __restrict__ log_dt,
    const float* __restrict__ log_A_real,
    const float* __restrict__ A_imag,
    const float* __restrict__ VinvB_real,
    const float* __restrict__ VinvB_imag,
    const float* __restrict__ CV_real,
    const float* __restrict__ CV_imag,
    float* __restrict__ out)
{
    __shared__ float s_a2[NN], s_thr[NN], s_R[NN], s_phr[NN];

    const int bid   = blockIdx.x;
    const int h     = bid >> 3;   // 8 blocks per h row
    const int chunk = bid & 7;    // which 1024-wide l chunk
    const int tid   = threadIdx.x;

    if (tid < NN) {
        const int n   = tid;
        const int idx = h * NN + n;
        const float dt  = __expf(log_dt[h]);
        const float Are = -__expf(log_A_real[idx]);
        const float Aim = A_imag[idx];
        const float a   = dt * Are;   // per-step log decay (negative)
        const float th  = dt * Aim;   // per-step phase (radians)

        // A_bar - 1 = e^{a}(cos th + i sin th) - 1
        const float er = __expf(a);
        float s, c;
        __sincosf(th, &s, &c);
        const float Abr = __fmaf_rn(er, c, -1.0f);
        const float Abi = er * s;

        // B_bar = (A_bar - 1) * B / A   (complex)
        const float Br = VinvB_real[idx], Bi = VinvB_imag[idx];
        const float numr = Abr * Br - Abi * Bi;
        const float numi = Abr * Bi + Abi * Br;
        const float invden = 1.0f / (Are * Are + Aim * Aim);
        const float Bbr = (numr * Are + numi * Aim) * invden;
        const float Bbi = (numi * Are - numr * Aim) * invden;

        // w = C * B_bar
        const float Cr = CV_real[idx], Ci = CV_imag[idx];
        const float wr = Cr * Bbr - Ci * Bbi;
        const float wi = Cr * Bbi + Ci * Bbr;

        const float INV2PI = 0.15915494309189533577f;
        s_a2[n]  = a * 1.44269504088896340736f;  // log2(e)
        s_thr[n] = th * INV2PI;
        s_R[n]   = sqrtf(wr * wr + wi * wi);
        s_phr[n] = atan2f(wi, wr) * INV2PI;
    }
    __syncthreads();

    float a2[NN], thr[NN], Rv[NN], phr[NN];
    #pragma unroll
    for (int n = 0; n < NN; ++n) {
        a2[n] = s_a2[n]; thr[n] = s_thr[n]; Rv[n] = s_R[n]; phr[n] = s_phr[n];
    }

    const int l0 = (chunk << 10) + (tid << 2);  // 256 threads x float4 = 1024
    float4 o;
    float* op = reinterpret_cast<float*>(&o);
    #pragma unroll
    for (int j = 0; j < 4; ++j) {
        const float lf = (float)(l0 + j);
        float acc = 0.0f;
        #pragma unroll
        for (int n = 0; n < NN; ++n) {
            const float e = __builtin_amdgcn_exp2f(a2[n] * lf);
            const float f = __builtin_amdgcn_fractf(__fmaf_rn(thr[n], lf, phr[n]));
            const float c = __builtin_amdgcn_cosf(f);   // v_cos takes revolutions
            acc = __fmaf_rn(Rv[n], e * c, acc);
        }
        op[j] = acc;
    }
    *reinterpret_cast<float4*>(out + (size_t)h * LL + l0) = o;
}

extern "C" void kernel_launch(void* const* d_in, const int* in_sizes, int n_in,
                              void* d_out, int out_size, void* d_ws, size_t ws_size,
                              hipStream_t stream) {
    const float* log_dt     = (const float*)d_in[0];
    const float* log_A_real = (const float*)d_in[1];
    const float* A_imag     = (const float*)d_in[2];
    const float* VinvB_real = (const float*)d_in[3];
    const float* VinvB_imag = (const float*)d_in[4];
    const float* CV_real    = (const float*)d_in[5];
    const float* CV_imag    = (const float*)d_in[6];
    float* out = (float*)d_out;

    dim3 grid(HH * (LL / 1024));  // 16384 blocks: one (h, 1024-chunk) each
    dim3 block(256);
    pmsn_kernel<<<grid, block, 0, stream>>>(log_dt, log_A_real, A_imag,
        VinvB_real, VinvB_imag, CV_real, CV_imag, out);
}

// Round 2
// 19.360 us; speedup vs baseline: 1.4140x; 1.4140x over previous
//
#include <hip/hip_runtime.h>
#include <math.h>

// PMSN Vandermonde kernel via complex recurrence.
// out[h,l] = Re( sum_n w_n * Abar_n^l ),  w = C*B_bar, Abar = exp(dt*A).
// H=2048, N=4, L=8192 -> 64 MiB fp32 output (write-bound target ~10.5us).
//
// One block (256 thr) per h. Thread t owns l = 4t..4t+3 (+1024 per iter, 8 iters).
// State: z[j][n] = w_n * Abar_n^(4t+j+1024*it), advanced by M_n = Abar_n^1024.
// Initial phases and the 1024-step phase are computed with double-precision
// fract (fp32 fract at ~300 revolutions would lose ~2e-4 rad/jump).

#define HH 2048
#define NN 4
#define LL 8192

__global__ __launch_bounds__(256) void pmsn_kernel(
    const float* __restrict__ log_dt,
    const float* __restrict__ log_A_real,
    const float* __restrict__ A_imag,
    const float* __restrict__ VinvB_real,
    const float* __restrict__ VinvB_imag,
    const float* __restrict__ CV_real,
    const float* __restrict__ CV_imag,
    float* __restrict__ out)
{
    __shared__ double s_thr[NN];          // revolutions per step
    __shared__ float2 s_w[NN];            // C * B_bar
    __shared__ float2 s_Ab[NN];           // Abar (1-step multiplier)
    __shared__ float2 s_M[NN];            // Abar^1024 (jump multiplier)
    __shared__ float  s_a2[NN];           // log2-decay per step

    const int h   = blockIdx.x;
    const int tid = threadIdx.x;

    if (tid < NN) {
        const int n = tid, idx = h * NN + n;
        const float dt  = __expf(log_dt[h]);
        const float Are = -__expf(log_A_real[idx]);
        const float Aim = A_imag[idx];
        const double dt_d  = (double)dt;
        const double a_d   = dt_d * (double)Are;                  // ln-decay/step
        const double th_d  = dt_d * (double)Aim;                  // rad/step
        const double thr_d = th_d * 0.15915494309189533577;       // rev/step
        const double a2_d  = a_d * 1.4426950408889634074;         // log2/step

        // w = C * B_bar,  B_bar = (Abar - 1) * B / A
        const float er = __expf((float)a_d);
        float sn, cs; __sincosf((float)th_d, &sn, &cs);
        const float Am1r = __fmaf_rn(er, cs, -1.0f);
        const float Am1i = er * sn;
        const float Br = VinvB_real[idx], Bi = VinvB_imag[idx];
        const float numr = Am1r * Br - Am1i * Bi;
        const float numi = Am1r * Bi + Am1i * Br;
        const float invden = 1.0f / (Are * Are + Aim * Aim);
        const float Bbr = (numr * Are + numi * Aim) * invden;
        const float Bbi = (numi * Are - numr * Aim) * invden;
        const float Cr = CV_real[idx], Ci = CV_imag[idx];
        s_w[n] = make_float2(Cr * Bbr - Ci * Bbi, Cr * Bbi + Ci * Bbr);

        s_thr[n] = thr_d;
        s_a2[n]  = (float)a2_d;

        // 1-step multiplier Abar
        {
            const float p = (float)(thr_d - floor(thr_d));
            const float e = __builtin_amdgcn_exp2f((float)a2_d);
            s_Ab[n] = make_float2(e * __builtin_amdgcn_cosf(p),
                                  e * __builtin_amdgcn_sinf(p));
        }
        // 1024-step multiplier Abar^1024 (phase via double fract)
        {
            const double t = thr_d * 1024.0;
            const float p = (float)(t - floor(t));
            const float e = __builtin_amdgcn_exp2f((float)(a2_d * 1024.0));
            s_M[n] = make_float2(e * __builtin_amdgcn_cosf(p),
                                 e * __builtin_amdgcn_sinf(p));
        }
    }
    __syncthreads();

    const int l0 = tid << 2;
    float zr[4][NN], zi[4][NN];
    float Mr[NN], Mi[NN];

    #pragma unroll
    for (int n = 0; n < NN; ++n) {
        const double ph_d = s_thr[n] * (double)l0;
        const float  ph   = (float)(ph_d - floor(ph_d));
        const float  c    = __builtin_amdgcn_cosf(ph);
        const float  s    = __builtin_amdgcn_sinf(ph);
        const float  env  = __builtin_amdgcn_exp2f(s_a2[n] * (float)l0);
        const float wr = s_w[n].x, wi = s_w[n].y;
        zr[0][n] = (wr * c - wi * s) * env;
        zi[0][n] = (wr * s + wi * c) * env;
        const float ar = s_Ab[n].x, ai = s_Ab[n].y;
        #pragma unroll
        for (int j = 1; j < 4; ++j) {
            zr[j][n] = zr[j-1][n] * ar - zi[j-1][n] * ai;
            zi[j][n] = zr[j-1][n] * ai + zi[j-1][n] * ar;
        }
        Mr[n] = s_M[n].x; Mi[n] = s_M[n].y;
    }

    float* outp = out + (size_t)h * LL + l0;
    #pragma unroll
    for (int it = 0; it < 8; ++it) {
        float4 o;
        o.x = (zr[0][0] + zr[0][1]) + (zr[0][2] + zr[0][3]);
        o.y = (zr[1][0] + zr[1][1]) + (zr[1][2] + zr[1][3]);
        o.z = (zr[2][0] + zr[2][1]) + (zr[2][2] + zr[2][3]);
        o.w = (zr[3][0] + zr[3][1]) + (zr[3][2] + zr[3][3]);
        *reinterpret_cast<float4*>(outp + it * 1024) = o;
        if (it < 7) {
            #pragma unroll
            for (int j = 0; j < 4; ++j) {
                #pragma unroll
                for (int n = 0; n < NN; ++n) {
                    const float r = zr[j][n] * Mr[n] - zi[j][n] * Mi[n];
                    const float i = zr[j][n] * Mi[n] + zi[j][n] * Mr[n];
                    zr[j][n] = r; zi[j][n] = i;
                }
            }
        }
    }
}

extern "C" void kernel_launch(void* const* d_in, const int* in_sizes, int n_in,
                              void* d_out, int out_size, void* d_ws, size_t ws_size,
                              hipStream_t stream) {
    const float* log_dt     = (const float*)d_in[0];
    const float* log_A_real = (const float*)d_in[1];
    const float* A_imag     = (const float*)d_in[2];
    const float* VinvB_real = (const float*)d_in[3];
    const float* VinvB_imag = (const float*)d_in[4];
    const float* CV_real    = (const float*)d_in[5];
    const float* CV_imag    = (const float*)d_in[6];
    float* out = (float*)d_out;

    dim3 grid(HH);      // one block per h
    dim3 block(256);
    pmsn_kernel<<<grid, block, 0, stream>>>(log_dt, log_A_real, A_imag,
        VinvB_real, VinvB_imag, CV_real, CV_imag, out);
}

// Round 3
// 17.489 us; speedup vs baseline: 1.5654x; 1.1070x over previous
//
#include <hip/hip_runtime.h>
#include <math.h>

// PMSN Vandermonde kernel via factored complex recurrence.
// out[h,l] = Re( sum_n w_n * Abar_n^l ),  w = C*B_bar, Abar = exp(dt*A).
// H=2048, N=4, L=8192 -> 64 MiB fp32 output (write-bound, floor ~10.5us).
//
// One block (256 thr) per h. Thread t at iteration it covers l = 4t+j+1024*it.
// State: y[n] = w_n * Abar^(4t+1024*it)   (4 complex regs, advanced by
// M = Abar^1024, 16 ops/iter).  Outputs: o[j] = Re sum_n y[n]*u[j][n] with
// u[j][n] = Abar^j wave-uniform constants held in SGPRs via readfirstlane
// (24 FMAs + 3 adds per 4 outputs).  ~11 lane-ops/output.
// All large-l phases use double-precision fract; the y chain is only 7
// fp32 complex muls long.

#define HH 2048
#define NN 4
#define LL 8192

__device__ __forceinline__ float rfl(float x) {
    return __int_as_float(__builtin_amdgcn_readfirstlane(__float_as_int(x)));
}

__global__ __launch_bounds__(256) void pmsn_kernel(
    const float* __restrict__ log_dt,
    const float* __restrict__ log_A_real,
    const float* __restrict__ A_imag,
    const float* __restrict__ VinvB_real,
    const float* __restrict__ VinvB_imag,
    const float* __restrict__ CV_real,
    const float* __restrict__ CV_imag,
    float* __restrict__ out)
{
    __shared__ double s_thr[NN];          // revolutions per step
    __shared__ float  s_a2[NN];           // log2-decay per step
    __shared__ float2 s_w[NN];            // C * B_bar
    __shared__ float2 s_u[3][NN];         // Abar^j, j=1..3
    __shared__ float2 s_M[NN];            // Abar^1024

    const int h   = blockIdx.x;
    const int tid = threadIdx.x;

    if (tid < NN) {
        const int n = tid, idx = h * NN + n;
        const float dt  = __expf(log_dt[h]);
        const float Are = -__expf(log_A_real[idx]);
        const float Aim = A_imag[idx];
        const double dt_d  = (double)dt;
        const double a_d   = dt_d * (double)Are;                  // ln-decay/step
        const double th_d  = dt_d * (double)Aim;                  // rad/step
        const double thr_d = th_d * 0.15915494309189533577;       // rev/step
        const double a2_d  = a_d * 1.4426950408889634074;         // log2/step

        // w = C * B_bar,  B_bar = (Abar - 1) * B / A
        const float er = __expf((float)a_d);
        float sn, cs; __sincosf((float)th_d, &sn, &cs);
        const float Am1r = __fmaf_rn(er, cs, -1.0f);
        const float Am1i = er * sn;
        const float Br = VinvB_real[idx], Bi = VinvB_imag[idx];
        const float numr = Am1r * Br - Am1i * Bi;
        const float numi = Am1r * Bi + Am1i * Br;
        const float invden = 1.0f / (Are * Are + Aim * Aim);
        const float Bbr = (numr * Are + numi * Aim) * invden;
        const float Bbi = (numi * Are - numr * Aim) * invden;
        const float Cr = CV_real[idx], Ci = CV_imag[idx];
        s_w[n] = make_float2(Cr * Bbr - Ci * Bbi, Cr * Bbi + Ci * Bbr);

        s_thr[n] = thr_d;
        s_a2[n]  = (float)a2_d;

        // u_j = Abar^j, j = 1..3 (computed directly for accuracy)
        #pragma unroll
        for (int j = 1; j <= 3; ++j) {
            const double t = thr_d * (double)j;
            const float p = (float)(t - floor(t));
            const float e = __builtin_amdgcn_exp2f((float)(a2_d * (double)j));
            s_u[j-1][n] = make_float2(e * __builtin_amdgcn_cosf(p),
                                      e * __builtin_amdgcn_sinf(p));
        }
        // M = Abar^1024 (phase via double fract)
        {
            const double t = thr_d * 1024.0;
            const float p = (float)(t - floor(t));
            const float e = __builtin_amdgcn_exp2f((float)(a2_d * 1024.0));
            s_M[n] = make_float2(e * __builtin_amdgcn_cosf(p),
                                 e * __builtin_amdgcn_sinf(p));
        }
    }
    __syncthreads();

    // Broadcast wave-uniform constants into SGPRs.
    float ur[3][NN], ui[3][NN], Mr[NN], Mi[NN];
    #pragma unroll
    for (int n = 0; n < NN; ++n) {
        #pragma unroll
        for (int j = 0; j < 3; ++j) {
            ur[j][n] = rfl(s_u[j][n].x);
            ui[j][n] = rfl(s_u[j][n].y);
        }
        Mr[n] = rfl(s_M[n].x);
        Mi[n] = rfl(s_M[n].y);
    }

    // Initialize y[n] = w_n * Abar^l0
    const int l0 = tid << 2;
    float yr[NN], yi[NN];
    #pragma unroll
    for (int n = 0; n < NN; ++n) {
        const double ph_d = s_thr[n] * (double)l0;
        const float  p    = (float)(ph_d - floor(ph_d));
        const float  c    = __builtin_amdgcn_cosf(p);
        const float  s    = __builtin_amdgcn_sinf(p);
        const float  env  = __builtin_amdgcn_exp2f(s_a2[n] * (float)l0);
        const float wr = s_w[n].x, wi = s_w[n].y;
        yr[n] = (wr * c - wi * s) * env;
        yi[n] = (wr * s + wi * c) * env;
    }

    float* outp = out + (size_t)h * LL + l0;
    #pragma unroll
    for (int it = 0; it < 8; ++it) {
        float4 o;
        o.x = (yr[0] + yr[1]) + (yr[2] + yr[3]);
        {
            float s0 = yr[0] * ur[0][0] - yi[0] * ui[0][0];
            float s1 = yr[1] * ur[0][1] - yi[1] * ui[0][1];
            float s2 = yr[2] * ur[0][2] - yi[2] * ui[0][2];
            float s3 = yr[3] * ur[0][3] - yi[3] * ui[0][3];
            o.y = (s0 + s1) + (s2 + s3);
        }
        {
            float s0 = yr[0] * ur[1][0] - yi[0] * ui[1][0];
            float s1 = yr[1] * ur[1][1] - yi[1] * ui[1][1];
            float s2 = yr[2] * ur[1][2] - yi[2] * ui[1][2];
            float s3 = yr[3] * ur[1][3] - yi[3] * ui[1][3];
            o.z = (s0 + s1) + (s2 + s3);
        }
        {
            float s0 = yr[0] * ur[2][0] - yi[0] * ui[2][0];
            float s1 = yr[1] * ur[2][1] - yi[1] * ui[2][1];
            float s2 = yr[2] * ur[2][2] - yi[2] * ui[2][2];
            float s3 = yr[3] * ur[2][3] - yi[3] * ui[2][3];
            o.w = (s0 + s1) + (s2 + s3);
        }
        *reinterpret_cast<float4*>(outp + it * 1024) = o;
        if (it < 7) {
            #pragma unroll
            for (int n = 0; n < NN; ++n) {
                const float r = yr[n] * Mr[n] - yi[n] * Mi[n];
                const float i = yr[n] * Mi[n] + yi[n] * Mr[n];
                yr[n] = r; yi[n] = i;
            }
        }
    }
}

extern "C" void kernel_launch(void* const* d_in, const int* in_sizes, int n_in,
                              void* d_out, int out_size, void* d_ws, size_t ws_size,
                              hipStream_t stream) {
    const float* log_dt     = (const float*)d_in[0];
    const float* log_A_real = (const float*)d_in[1];
    const float* A_imag     = (const float*)d_in[2];
    const float* VinvB_real = (const float*)d_in[3];
    const float* VinvB_imag = (const float*)d_in[4];
    const float* CV_real    = (const float*)d_in[5];
    const float* CV_imag    = (const float*)d_in[6];
    float* out = (float*)d_out;

    dim3 grid(HH);      // one block per h
    dim3 block(256);
    pmsn_kernel<<<grid, block, 0, stream>>>(log_dt, log_A_real, A_imag,
        VinvB_real, VinvB_imag, CV_real, CV_imag, out);
}